// Round 8
// baseline (327.848 us; speedup 1.0000x reference)
//
#include <hip/hip_runtime.h>

#define BATCH 32
#define NPTS  1024
#define NFEAT 256
#define NPROP 256
#define NSAMP 16

// flat output offsets (floats), in reference tuple order
#define O_OBJ    0
#define O_CENTER 16384
#define O_HS     40960
#define O_HRN    139264
#define O_HR     237568
#define O_SS     335872
#define O_SRN    483328
#define O_SR     925696
#define O_SEM    1368064
#define O_NX     1515520
#define O_INDS   1540096

typedef __attribute__((ext_vector_type(8))) short bf16x8;
typedef __attribute__((ext_vector_type(8))) unsigned short u16x8;
typedef __attribute__((ext_vector_type(2))) float f32x2;
typedef __attribute__((ext_vector_type(16))) float f32x16;

__device__ __forceinline__ unsigned short f2bf(float f) {
  unsigned u = __builtin_bit_cast(unsigned, f);
  u += 0x7fffu + ((u >> 16) & 1u);   // RNE to bf16
  return (unsigned short)(u >> 16);
}

// single-op DPP f32 max step (ctrl pattern hardware-validated R3-R6 + R1)
template<int CTRL>
__device__ __forceinline__ float dpp_maxf(float v) {
  int x = __builtin_amdgcn_update_dpp(__builtin_bit_cast(int, v),
          __builtin_bit_cast(int, v), CTRL, 0xf, 0xf, false);
  return fmaxf(v, __builtin_bit_cast(float, x));
}

// ---------------------------------------------------------------------------
// Kernel 1: blocks 0..31 = single-wave FPS for batch b (16 pts/lane, fully
// register-resident, barrier-free); blocks 32..255 = grid-stride prep.
// R8: __launch_bounds__(256, 1) unlocks the VGPR budget (R0's pin failed
// because the default occupancy target capped VGPR at ~40 -> forced spills);
// a ONE-TIME pre-loop opaque pin makes px/py/pz un-rematerializable.
// Per iter: one broadcast ds_read_b128, packed dist update, pk-max tree,
// 6x f32 DPP max, readlane, 16 ballots + SALU min-k scan. No barriers.
// Exact fp32 math (contract off); tie-break == jnp.argmax first-occurrence.
// ---------------------------------------------------------------------------
__global__ __launch_bounds__(256, 1) void fps_prep_kernel(
    const float* __restrict__ xyz,
    const float* __restrict__ feats,
    const float* __restrict__ w0, const float* __restrict__ w1,
    const float* __restrict__ w2, const float* __restrict__ w3,
    const float* __restrict__ b0, const float* __restrict__ g0, const float* __restrict__ be0,
    const float* __restrict__ b1, const float* __restrict__ g1, const float* __restrict__ be1,
    const float* __restrict__ b2, const float* __restrict__ g2, const float* __restrict__ be2,
    const float* __restrict__ wf1, const float* __restrict__ bf1,
    const float* __restrict__ gf1, const float* __restrict__ bef1,
    const float* __restrict__ wf2, const float* __restrict__ bf2,
    const float* __restrict__ gf2, const float* __restrict__ bef2,
    unsigned short* __restrict__ fbf,
    unsigned short* __restrict__ w0bt, unsigned short* __restrict__ w1bt,
    unsigned short* __restrict__ w2bt,
    unsigned short* __restrict__ wfb1, unsigned short* __restrict__ wfb2,
    unsigned short* __restrict__ w3pb,
    float* __restrict__ gb0, float* __restrict__ gb1, float* __restrict__ gb2,
    float* __restrict__ gbf1, float* __restrict__ gbf2,
    float* __restrict__ o_nx,
    float* __restrict__ o_inds)
{
#pragma clang fp contract(off)
  __shared__ float sxyz4[NPTS*4];          // [1024][4] for b128 broadcast
  __shared__ int   sInd[NPROP];

  const int tid = threadIdx.x;

  if (blockIdx.x < BATCH) {
    if (tid >= 64) return;                 // FPS is one wave; spares exit
    // ================= FPS: single wave, no barriers =================
    const int b = blockIdx.x;
    const int t = tid;
    const float* xb = xyz + b * NPTS * 3;
    for (int k = t; k < NPTS; k += 64) {
      sxyz4[k*4+0] = xb[k*3+0];
      sxyz4[k*4+1] = xb[k*3+1];
      sxyz4[k*4+2] = xb[k*3+2];
    }
    // wave-coherent LDS: compiler inserts lgkmcnt waits on dependency

    f32x2 px[8], py[8], pz[8], dd[8];
#pragma unroll
    for (int a = 0; a < 8; ++a) {
      int k0 = t + 128*a, k1 = k0 + 64;
      px[a] = (f32x2){sxyz4[k0*4+0], sxyz4[k1*4+0]};
      py[a] = (f32x2){sxyz4[k0*4+1], sxyz4[k1*4+1]};
      pz[a] = (f32x2){sxyz4[k0*4+2], sxyz4[k1*4+2]};
      dd[a] = (f32x2){1e10f, 1e10f};
    }
    // ONE-TIME opaque pin: origins become un-rematerializable; with the
    // (256,1) VGPR budget the allocator keeps all 48 coord regs resident.
#pragma unroll
    for (int a = 0; a < 8; ++a) {
      asm volatile("" : "+v"(px[a]), "+v"(py[a]), "+v"(pz[a]));
    }

    int last = 0;
    for (int it = 1; it < NPROP; ++it) {
      float4 lp = *(const float4*)(sxyz4 + last*4);   // one ds_read_b128
      f32x2 vlx = (f32x2){lp.x, lp.x};
      f32x2 vly = (f32x2){lp.y, lp.y};
      f32x2 vlz = (f32x2){lp.z, lp.z};
#pragma unroll
      for (int a = 0; a < 8; ++a) {
        f32x2 dx = px[a] - vlx;
        f32x2 dy = py[a] - vly;
        f32x2 dz = pz[a] - vlz;
        f32x2 d  = dx*dx + dy*dy + dz*dz;   // contract off: mul,mul,mul,add,add
        dd[a] = __builtin_elementwise_min(dd[a], d);
      }
      // in-lane max: packed tree (depth 3) + final component max
      f32x2 m0 = __builtin_elementwise_max(dd[0], dd[1]);
      f32x2 m1 = __builtin_elementwise_max(dd[2], dd[3]);
      f32x2 m2 = __builtin_elementwise_max(dd[4], dd[5]);
      f32x2 m3 = __builtin_elementwise_max(dd[6], dd[7]);
      f32x2 mm = __builtin_elementwise_max(__builtin_elementwise_max(m0, m1),
                                           __builtin_elementwise_max(m2, m3));
      float m = fmaxf(mm[0], mm[1]);
      // cross-lane f32 max -> lane 63 (validated ladder)
      m = dpp_maxf<0x111>(m);   // row_shr:1
      m = dpp_maxf<0x112>(m);   // row_shr:2
      m = dpp_maxf<0x114>(m);   // row_shr:4
      m = dpp_maxf<0x118>(m);   // row_shr:8
      m = dpp_maxf<0x142>(m);   // row_bcast:15
      m = dpp_maxf<0x143>(m);   // row_bcast:31
      float gmax = __builtin_bit_cast(float,
          __builtin_amdgcn_readlane(__builtin_bit_cast(int, m), 63));
      // index recovery: 16 ballots (k = 64*j + lane, j = 2a+c) + SALU min-k scan
      unsigned long long msk[16];
#pragma unroll
      for (int a = 0; a < 8; ++a) {
        msk[2*a]   = __ballot(dd[a][0] == gmax);
        msk[2*a+1] = __ballot(dd[a][1] == gmax);
      }
      int nl = 0;
#pragma unroll
      for (int j = 15; j >= 0; --j) {
        unsigned long long mj = msk[j];
        if (mj) nl = j*64 + (int)__builtin_ctzll(mj);
      }
      last = nl;
      if (t == 0) sInd[it] = last;
    }
    if (t == 0) sInd[0] = 0;

    for (int s = t; s < NPROP; s += 64) {
      int ind = sInd[s];
      o_inds[b*NPROP + s] = (float)ind;
      float* nx = o_nx + (b*NPROP + s)*3;
      nx[0] = sxyz4[ind*4+0]; nx[1] = sxyz4[ind*4+1]; nx[2] = sxyz4[ind*4+2];
    }
  } else {
    // ================= prep: 224 blocks x 256 threads, grid-stride =========
    const int pid = (blockIdx.x - BATCH) * 256 + tid;    // 0..57343
    const int PSTRIDE = (256 - BATCH) * 256;             // 57344
    // feats -> bf16 (8 floats per step)
    for (int i = pid; i < (BATCH*NPTS*NFEAT)/8; i += PSTRIDE) {
      size_t o = (size_t)i * 8;
      float4 f0 = *(const float4*)(feats + o);
      float4 f1 = *(const float4*)(feats + o + 4);
      u16x8 v;
      v[0]=f2bf(f0.x); v[1]=f2bf(f0.y); v[2]=f2bf(f0.z); v[3]=f2bf(f0.w);
      v[4]=f2bf(f1.x); v[5]=f2bf(f1.y); v[6]=f2bf(f1.z); v[7]=f2bf(f1.w);
      *(u16x8*)(fbf + o) = v;
    }
    // weights + fused bias terms
    for (int id = pid; id < 119424; id += PSTRIDE) {
      if (id < 36864) {                       // w0bt [128][288]
        int n = id / 288, k = id - 288*n;
        float v = 0.f;
        if (k < 256) v = w0[(k+3)*128 + n];
        else if (k < 259) v = w0[(k-256)*128 + n];
        w0bt[id] = f2bf(v);
      } else if (id < 53248) {                // w1bt [128][128]
        int j = id - 36864; int n = j >> 7, k = j & 127;
        w1bt[j] = f2bf(w1[k*128 + n]);
      } else if (id < 69632) {                // w2bt [128][128]
        int j = id - 53248; int n = j >> 7, k = j & 127;
        w2bt[j] = f2bf(w2[k*128 + n]);
      } else if (id < 86016) {                // wfb1 [128][128]
        int j = id - 69632; int n = j >> 7, k = j & 127;
        wfb1[j] = f2bf(wf1[k*128 + n]);
      } else if (id < 102400) {               // wfb2 [128][128]
        int j = id - 86016; int n = j >> 7, k = j & 127;
        wfb2[j] = f2bf(wf2[k*128 + n]);
      } else if (id < 118784) {               // w3pb [128][128] zero-padded
        int j = id - 102400; int n = j >> 7, k = j & 127;
        w3pb[j] = (n < 119) ? f2bf(w3[k*119 + n]) : (unsigned short)0;
      } else if (id < 118912) {
        int c = id - 118784; gb0[c] = fmaf(g0[c], b0[c], be0[c]);
      } else if (id < 119040) {
        int c = id - 118912; gb1[c] = fmaf(g1[c], b1[c], be1[c]);
      } else if (id < 119168) {
        int c = id - 119040; gb2[c] = fmaf(g2[c], b2[c], be2[c]);
      } else if (id < 119296) {
        int c = id - 119168; gbf1[c] = fmaf(gf1[c], bf1[c], bef1[c]);
      } else {
        int c = id - 119296; gbf2[c] = fmaf(gf2[c], bf2[c], bef2[c]);
      }
    }
  }
}

// ---------------------------------------------------------------------------
// Kernel 2a: ball query (in-wave) + grouped MLP via 32x32x16 bf16 MFMA.
// 256-thread blocks = 4 waves; each wave: BQ for its 2 proposals -> LDS,
// then the MLP with a private 8 KiB act slice. Emits bf16 features for the
// MFMA FC head.
// ---------------------------------------------------------------------------
__global__ __launch_bounds__(256) void group_mlp_kernel(
    const float* __restrict__ xyz,
    const unsigned short* __restrict__ fbf,
    const unsigned short* __restrict__ w0bt,
    const unsigned short* __restrict__ w1bt,
    const unsigned short* __restrict__ w2bt,
    const float* __restrict__ g0, const float* __restrict__ gb0,
    const float* __restrict__ g1, const float* __restrict__ gb1,
    const float* __restrict__ g2, const float* __restrict__ gb2,
    const float* __restrict__ onx,
    unsigned short* __restrict__ featbf)
{
  __shared__ __align__(16) unsigned short act[4*4096];   // 32 KiB (8 KiB/wave)
  __shared__ int sIdxAll[4][32];                         // [wave][2 props x 16]

  const int tid  = threadIdx.x;
  const int wave = tid >> 6;
  const int lane = tid & 63;
  const int s  = lane & 31;        // A row (sample) / B-D col bits (channel)
  const int h  = lane >> 5;        // K-half
  const int n0 = s;                // channel lane for B/D
  const int gw = blockIdx.x * 4 + wave;       // global wave id, 0..4095
  const int p  = gw * 2 + (s >> 4);           // this lane's A-row proposal
  const int b  = gw >> 7;                     // batch
  const int samp = s & 15;
  unsigned short* actw = act + wave * 4096;
  int* sIdxW = sIdxAll[wave];

  // ---- in-wave ball query for this wave's 2 proposals (exact fp32 math)
  {
    const float* xb = xyz + b * NPTS * 3;
    const int k0 = lane * 16;
#pragma unroll
    for (int pi = 0; pi < 2; ++pi) {
      const int pp = gw*2 + pi;
      const float qx = onx[pp*3+0];
      const float qy = onx[pp*3+1];
      const float qz = onx[pp*3+2];
      unsigned mask = 0u;
#pragma unroll
      for (int j = 0; j < 16; ++j) {
        int k = k0 + j;
        float dx = __fsub_rn(qx, xb[k*3+0]);
        float dy = __fsub_rn(qy, xb[k*3+1]);
        float dz = __fsub_rn(qz, xb[k*3+2]);
        float d2 = __fadd_rn(__fadd_rn(__fmul_rn(dx,dx), __fmul_rn(dy,dy)), __fmul_rn(dz,dz));
        if (d2 < 0.09f) mask |= (1u << j);
      }
      int cnt  = __popc(mask);
      int incl = cnt;
#pragma unroll
      for (int ofs = 1; ofs < 64; ofs <<= 1) {
        int v = __shfl_up(incl, ofs);
        if (lane >= ofs) incl += v;
      }
      int start = incl - cnt;
      int total = __shfl(incl, 63);
      int fc = mask ? (k0 + __ffs(mask) - 1) : 0x7fffffff;
#pragma unroll
      for (int m = 32; m >= 1; m >>= 1) fc = min(fc, __shfl_xor(fc, m));
      int first = (total > 0) ? fc : (NPTS - 1);
      int* dst = sIdxW + pi*16;
      if (lane >= total && lane < NSAMP) dst[lane] = first;
      int pos = start;
      unsigned mm = mask;
      while (mm && pos < NSAMP) {
        int j = __ffs(mm) - 1; mm &= mm - 1;
        dst[pos] = k0 + j;
        ++pos;
      }
    }
  }
  __syncthreads();   // all 4 waves reach this; also orders sIdx writes

  const int idx = sIdxW[(s>>4)*16 + samp];
  const unsigned short* arow = fbf + ((size_t)(b*NPTS + idx) << 8);

  // gxyz A-fragment for kstep 16 (k=256..258 live in h==0 lanes)
  bf16x8 agx = (bf16x8){0,0,0,0,0,0,0,0};
  if (h == 0) {
    const float* pp = xyz + (size_t)(b*NPTS + idx)*3;
    agx[0] = (short)f2bf((pp[0] - onx[p*3+0]) * (1.0f/0.3f));
    agx[1] = (short)f2bf((pp[1] - onx[p*3+1]) * (1.0f/0.3f));
    agx[2] = (short)f2bf((pp[2] - onx[p*3+2]) * (1.0f/0.3f));
  }

  f32x16 acc[4];
#pragma unroll
  for (int nt = 0; nt < 4; ++nt) acc[nt] = (f32x16)(0.f);

  // ---- layer 0: K = 259 (ksteps 0..15 feats, 16 = gxyz; zero kstep skipped)
#pragma unroll 4
  for (int ks = 0; ks < 16; ++ks) {
    bf16x8 a = *(const bf16x8*)(arow + ks*16 + h*8);
    const unsigned short* wp = w0bt + (size_t)n0*288 + ks*16 + h*8;
#pragma unroll
    for (int nt = 0; nt < 4; ++nt) {
      bf16x8 bb = *(const bf16x8*)(wp + (size_t)nt*32*288);
      acc[nt] = __builtin_amdgcn_mfma_f32_32x32x16_bf16(a, bb, acc[nt], 0, 0, 0);
    }
  }
  {
    const unsigned short* wp = w0bt + (size_t)n0*288 + 256 + h*8;
#pragma unroll
    for (int nt = 0; nt < 4; ++nt) {
      bf16x8 bb = *(const bf16x8*)(wp + (size_t)nt*32*288);
      acc[nt] = __builtin_amdgcn_mfma_f32_32x32x16_bf16(agx, bb, acc[nt], 0, 0, 0);
    }
  }
  // act0 -> LDS (relu(g*x+gb)), swizzled layout
#pragma unroll
  for (int nt = 0; nt < 4; ++nt) {
    int c = nt*32 + n0;
    int gch = c >> 3;
    float gg = g0[c], gv = gb0[c];
    int base = gch*256 + (c & 7);
#pragma unroll
    for (int r = 0; r < 16; ++r) {
      int srow = (r & 3) + 8*(r >> 2) + 4*h;
      float v = fmaxf(fmaf(gg, acc[nt][r], gv), 0.f);
      actw[base + ((srow + 2*gch) & 31)*8] = f2bf(v);
    }
  }
  __syncthreads();

  // ---- layer 1: K = 128
#pragma unroll
  for (int nt = 0; nt < 4; ++nt) acc[nt] = (f32x16)(0.f);
#pragma unroll 4
  for (int ks = 0; ks < 8; ++ks) {
    int g = ks*2 + h;
    bf16x8 a = *(const bf16x8*)(actw + g*256 + ((s + 2*g) & 31)*8);
    const unsigned short* wp = w1bt + (size_t)n0*128 + ks*16 + h*8;
#pragma unroll
    for (int nt = 0; nt < 4; ++nt) {
      bf16x8 bb = *(const bf16x8*)(wp + (size_t)nt*32*128);
      acc[nt] = __builtin_amdgcn_mfma_f32_32x32x16_bf16(a, bb, acc[nt], 0, 0, 0);
    }
  }
  __syncthreads();
#pragma unroll
  for (int nt = 0; nt < 4; ++nt) {
    int c = nt*32 + n0;
    int gch = c >> 3;
    float gg = g1[c], gv = gb1[c];
    int base = gch*256 + (c & 7);
#pragma unroll
    for (int r = 0; r < 16; ++r) {
      int srow = (r & 3) + 8*(r >> 2) + 4*h;
      float v = fmaxf(fmaf(gg, acc[nt][r], gv), 0.f);
      actw[base + ((srow + 2*gch) & 31)*8] = f2bf(v);
    }
  }
  __syncthreads();

  // ---- layer 2: K = 128, fused maxpool over each proposal's 16 samples
#pragma unroll
  for (int nt = 0; nt < 4; ++nt) acc[nt] = (f32x16)(0.f);
#pragma unroll 4
  for (int ks = 0; ks < 8; ++ks) {
    int g = ks*2 + h;
    bf16x8 a = *(const bf16x8*)(actw + g*256 + ((s + 2*g) & 31)*8);
    const unsigned short* wp = w2bt + (size_t)n0*128 + ks*16 + h*8;
#pragma unroll
    for (int nt = 0; nt < 4; ++nt) {
      bf16x8 bb = *(const bf16x8*)(wp + (size_t)nt*32*128);
      acc[nt] = __builtin_amdgcn_mfma_f32_32x32x16_bf16(a, bb, acc[nt], 0, 0, 0);
    }
  }
#pragma unroll
  for (int nt = 0; nt < 4; ++nt) {
    int c = nt*32 + n0;
    float gg = g2[c], gv = gb2[c];
    float m0 = 0.f, m1 = 0.f;   // relu => max >= 0
#pragma unroll
    for (int r = 0; r < 8; ++r)
      m0 = fmaxf(m0, fmaxf(fmaf(gg, acc[nt][r], gv), 0.f));       // rows 0..15  (prop lo)
#pragma unroll
    for (int r = 8; r < 16; ++r)
      m1 = fmaxf(m1, fmaxf(fmaf(gg, acc[nt][r], gv), 0.f));       // rows 16..31 (prop hi)
    m0 = fmaxf(m0, __shfl_xor(m0, 32));
    m1 = fmaxf(m1, __shfl_xor(m1, 32));
    float vout = h ? m1 : m0;
    featbf[(size_t)(gw*2 + h)*128 + c] = f2bf(vout);
  }
}

// ---------------------------------------------------------------------------
// Kernel 2b: FC head via 32x32x16 bf16 MFMA — one wave per 32 proposals,
// barrier-free (private LDS slice; DS ops are in-order within a wave).
// Fragment/swizzle code identical to group_mlp layers 1/2 (validated).
// ---------------------------------------------------------------------------
__global__ __launch_bounds__(64) void fc_head_kernel(
    const unsigned short* __restrict__ featbf,
    const float* __restrict__ onx,
    const float* __restrict__ msize,
    const unsigned short* __restrict__ wfb1,
    const float* __restrict__ gf1, const float* __restrict__ gbf1,
    const unsigned short* __restrict__ wfb2,
    const float* __restrict__ gf2, const float* __restrict__ gbf2,
    const unsigned short* __restrict__ w3pb,
    const float* __restrict__ b3,
    float* __restrict__ out)
{
  __shared__ __align__(16) unsigned short actw[4096];   // 8 KiB, one wave
  const int lane = threadIdx.x;
  const int s  = lane & 31;        // A row (proposal) / B-D col bits
  const int h  = lane >> 5;        // K-half
  const int n0 = s;
  const int p0 = blockIdx.x * 32;  // this wave's 32 proposals

  f32x16 acc[4];

  // ---- FC1 (relu6): A = featbf rows p0..p0+31, K = 128
#pragma unroll
  for (int nt = 0; nt < 4; ++nt) acc[nt] = (f32x16)(0.f);
#pragma unroll
  for (int ks = 0; ks < 8; ++ks) {
    bf16x8 a = *(const bf16x8*)(featbf + (((size_t)(p0 + s)) << 7) + ks*16 + h*8);
    const unsigned short* wp = wfb1 + (size_t)n0*128 + ks*16 + h*8;
#pragma unroll
    for (int nt = 0; nt < 4; ++nt) {
      bf16x8 bb = *(const bf16x8*)(wp + (size_t)nt*32*128);
      acc[nt] = __builtin_amdgcn_mfma_f32_32x32x16_bf16(a, bb, acc[nt], 0, 0, 0);
    }
  }
#pragma unroll
  for (int nt = 0; nt < 4; ++nt) {
    int c = nt*32 + n0;
    int gch = c >> 3;
    float gg = gf1[c], gv = gbf1[c];
    int base = gch*256 + (c & 7);
#pragma unroll
    for (int r = 0; r < 16; ++r) {
      int srow = (r & 3) + 8*(r >> 2) + 4*h;
      float v = fminf(fmaxf(fmaf(gg, acc[nt][r], gv), 0.f), 6.f);
      actw[base + ((srow + 2*gch) & 31)*8] = f2bf(v);
    }
  }

  // ---- FC2 (relu6): K = 128 from LDS
#pragma unroll
  for (int nt = 0; nt < 4; ++nt) acc[nt] = (f32x16)(0.f);
#pragma unroll
  for (int ks = 0; ks < 8; ++ks) {
    int g = ks*2 + h;
    bf16x8 a = *(const bf16x8*)(actw + g*256 + ((s + 2*g) & 31)*8);
    const unsigned short* wp = wfb2 + (size_t)n0*128 + ks*16 + h*8;
#pragma unroll
    for (int nt = 0; nt < 4; ++nt) {
      bf16x8 bb = *(const bf16x8*)(wp + (size_t)nt*32*128);
      acc[nt] = __builtin_amdgcn_mfma_f32_32x32x16_bf16(a, bb, acc[nt], 0, 0, 0);
    }
  }
#pragma unroll
  for (int nt = 0; nt < 4; ++nt) {
    int c = nt*32 + n0;
    int gch = c >> 3;
    float gg = gf2[c], gv = gbf2[c];
    int base = gch*256 + (c & 7);
#pragma unroll
    for (int r = 0; r < 16; ++r) {
      int srow = (r & 3) + 8*(r >> 2) + 4*h;
      float v = fminf(fmaxf(fmaf(gg, acc[nt][r], gv), 0.f), 6.f);
      actw[base + ((srow + 2*gch) & 31)*8] = f2bf(v);
    }
  }

  // ---- FC3: K = 128, scatter with transforms
#pragma unroll
  for (int nt = 0; nt < 4; ++nt) acc[nt] = (f32x16)(0.f);
#pragma unroll
  for (int ks = 0; ks < 8; ++ks) {
    int g = ks*2 + h;
    bf16x8 a = *(const bf16x8*)(actw + g*256 + ((s + 2*g) & 31)*8);
    const unsigned short* wp = w3pb + (size_t)n0*128 + ks*16 + h*8;
#pragma unroll
    for (int nt = 0; nt < 4; ++nt) {
      bf16x8 bb = *(const bf16x8*)(wp + (size_t)nt*32*128);
      acc[nt] = __builtin_amdgcn_mfma_f32_32x32x16_bf16(a, bb, acc[nt], 0, 0, 0);
    }
  }
  const float HRC = (float)(3.14159265359 / 12.0);
#pragma unroll
  for (int nt = 0; nt < 4; ++nt) {
    int c = nt*32 + n0;
    if (c >= 119) continue;
    float b3v = b3[c];
#pragma unroll
    for (int r = 0; r < 16; ++r) {
      int srow = (r & 3) + 8*(r >> 2) + 4*h;
      int bp = p0 + srow;
      float v = acc[nt][r] + b3v;
      if (c < 3) {
        out[O_CENTER + bp*3 + c] = onx[bp*3 + c] + v;
      } else if (c < 5) {
        out[O_OBJ + bp*2 + (c-3)] = v;
      } else if (c < 17) {
        out[O_HS + bp*12 + (c-5)] = v;
      } else if (c < 35) {
        out[O_SS + bp*18 + (c-17)] = v;
      } else if (c < 47) {
        int a2 = c - 35;
        out[O_HRN + bp*12 + a2] = v;
        out[O_HR  + bp*12 + a2] = v * HRC;
      } else if (c < 101) {
        int a2 = c - 47;
        out[O_SRN + bp*54 + a2] = v;
        out[O_SR  + bp*54 + a2] = v * msize[a2];
      } else {
        int a2 = c - 101;
        out[O_SEM + bp*18 + a2] = v;
      }
    }
  }
}

// ---------------------------------------------------------------------------
extern "C" void kernel_launch(void* const* d_in, const int* in_sizes, int n_in,
                              void* d_out, int out_size, void* d_ws, size_t ws_size,
                              hipStream_t stream) {
  (void)in_sizes; (void)n_in; (void)out_size; (void)ws_size;
  const float* xyz   = (const float*)d_in[0];
  const float* feats = (const float*)d_in[1];
  const float* msize = (const float*)d_in[2];
  const float* w0  = (const float*)d_in[3];
  const float* b0  = (const float*)d_in[4];
  const float* g0  = (const float*)d_in[5];
  const float* be0 = (const float*)d_in[6];
  const float* w1  = (const float*)d_in[7];
  const float* b1  = (const float*)d_in[8];
  const float* g1  = (const float*)d_in[9];
  const float* be1 = (const float*)d_in[10];
  const float* w2  = (const float*)d_in[11];
  const float* b2  = (const float*)d_in[12];
  const float* g2  = (const float*)d_in[13];
  const float* be2 = (const float*)d_in[14];
  const float* wf1  = (const float*)d_in[15];
  const float* bf1  = (const float*)d_in[16];
  const float* gf1  = (const float*)d_in[17];
  const float* bef1 = (const float*)d_in[18];
  const float* wf2  = (const float*)d_in[19];
  const float* bf2  = (const float*)d_in[20];
  const float* gf2  = (const float*)d_in[21];
  const float* bef2 = (const float*)d_in[22];
  const float* w3 = (const float*)d_in[23];
  const float* b3 = (const float*)d_in[24];

  float* out = (float*)d_out;

  // workspace layout (bytes) — stays within the previously-used footprint
  char* wsb = (char*)d_ws;
  unsigned short* wfb1   = (unsigned short*)(wsb + 0);          //  32 KiB
  unsigned short* wfb2   = (unsigned short*)(wsb + 32768);      //  32 KiB
  unsigned short* w3pb   = (unsigned short*)(wsb + 65536);      //  32 KiB
  float*          gbf1   = (float*)         (wsb + 98304);      //  512 B
  float*          gbf2   = (float*)         (wsb + 98816);      //  512 B
  unsigned short* fbf    = (unsigned short*)(wsb + 524288);     //  16 MiB
  unsigned short* featbf = (unsigned short*)(wsb + 17301504);   //   2 MiB
  unsigned short* w0bt   = (unsigned short*)(wsb + 21495808);   //  72 KiB
  unsigned short* w1bt   = (unsigned short*)(wsb + 21569536);   //  32 KiB
  unsigned short* w2bt   = (unsigned short*)(wsb + 21602304);   //  32 KiB
  float*          gb0    = (float*)         (wsb + 21635072);   //  512 B
  float*          gb1    = (float*)         (wsb + 21635584);   //  512 B
  float*          gb2    = (float*)         (wsb + 21636096);   //  512 B

  fps_prep_kernel<<<256, 256, 0, stream>>>(
      xyz, feats, w0, w1, w2, w3,
      b0, g0, be0, b1, g1, be1, b2, g2, be2,
      wf1, bf1, gf1, bef1, wf2, bf2, gf2, bef2,
      fbf, w0bt, w1bt, w2bt, wfb1, wfb2, w3pb,
      gb0, gb1, gb2, gbf1, gbf2,
      out + O_NX, out + O_INDS);
  group_mlp_kernel<<<(BATCH*NPROP)/8, 256, 0, stream>>>(
      xyz, fbf, w0bt, w1bt, w2bt,
      g0, gb0, g1, gb1, g2, gb2,
      out + O_NX, featbf);
  fc_head_kernel<<<(BATCH*NPROP)/32, 64, 0, stream>>>(
      featbf, out + O_NX, msize,
      wfb1, gf1, gbf1, wfb2, gf2, gbf2, w3pb, b3, out);
}

// Round 9
// 305.516 us; speedup vs baseline: 1.0731x; 1.0731x over previous
//
#include <hip/hip_runtime.h>

#define BATCH 32
#define NPTS  1024
#define NFEAT 256
#define NPROP 256
#define NSAMP 16

// flat output offsets (floats), in reference tuple order
#define O_OBJ    0
#define O_CENTER 16384
#define O_HS     40960
#define O_HRN    139264
#define O_HR     237568
#define O_SS     335872
#define O_SRN    483328
#define O_SR     925696
#define O_SEM    1368064
#define O_NX     1515520
#define O_INDS   1540096

typedef __attribute__((ext_vector_type(8))) short bf16x8;
typedef __attribute__((ext_vector_type(8))) unsigned short u16x8;
typedef __attribute__((ext_vector_type(2))) float f32x2;
typedef __attribute__((ext_vector_type(16))) float f32x16;

__device__ __forceinline__ unsigned short f2bf(float f) {
  unsigned u = __builtin_bit_cast(unsigned, f);
  u += 0x7fffu + ((u >> 16) & 1u);   // RNE to bf16
  return (unsigned short)(u >> 16);
}

// single-op DPP f32 max step (ctrl pattern hardware-validated R3-R6 + R1)
template<int CTRL>
__device__ __forceinline__ float dpp_maxf(float v) {
  int x = __builtin_amdgcn_update_dpp(__builtin_bit_cast(int, v),
          __builtin_bit_cast(int, v), CTRL, 0xf, 0xf, false);
  return fmaxf(v, __builtin_bit_cast(float, x));
}

// ---------------------------------------------------------------------------
// Kernel 1: blocks 0..31 = FPS for batch b (4 waves, 4 pts/lane); blocks
// 32..255 = grid-stride prep (streams concurrently; barriers block-scoped).
// FPS per iter (validated primitives only): broadcast ds_read_b128, packed
// dist update, f32 DPP ladder -> wave max, readlane, 4 ballots + scan ->
// per-wave min-index; lane0 packs (distbits<<32 | 1023-k) to a parity LDS
// slot; one __syncthreads; scalar u64 compares pick the winner.
// Exact fp32 math (contract off); tie-break == jnp.argmax first-occurrence.
// NOTE (R8 post-mortem): single-wave 16pts/lane variants are allocator-
// limited to VGPR=40 (LDS remat on the serial chain, ~120us) regardless of
// __launch_bounds__ or asm pins; this 4-wave structure is the measured
// optimum at 104.6us / 985 cyc/iter (R4).
// ---------------------------------------------------------------------------
__global__ __launch_bounds__(256) void fps_prep_kernel(
    const float* __restrict__ xyz,
    const float* __restrict__ feats,
    const float* __restrict__ w0, const float* __restrict__ w1,
    const float* __restrict__ w2, const float* __restrict__ w3,
    const float* __restrict__ b0, const float* __restrict__ g0, const float* __restrict__ be0,
    const float* __restrict__ b1, const float* __restrict__ g1, const float* __restrict__ be1,
    const float* __restrict__ b2, const float* __restrict__ g2, const float* __restrict__ be2,
    const float* __restrict__ wf1, const float* __restrict__ bf1,
    const float* __restrict__ gf1, const float* __restrict__ bef1,
    const float* __restrict__ wf2, const float* __restrict__ bf2,
    const float* __restrict__ gf2, const float* __restrict__ bef2,
    unsigned short* __restrict__ fbf,
    unsigned short* __restrict__ w0bt, unsigned short* __restrict__ w1bt,
    unsigned short* __restrict__ w2bt,
    unsigned short* __restrict__ wfb1, unsigned short* __restrict__ wfb2,
    unsigned short* __restrict__ w3pb,
    float* __restrict__ gb0, float* __restrict__ gb1, float* __restrict__ gb2,
    float* __restrict__ gbf1, float* __restrict__ gbf2,
    float* __restrict__ o_nx,
    float* __restrict__ o_inds)
{
#pragma clang fp contract(off)
  __shared__ float sxyz4[NPTS*4];          // [1024][4] for b128 broadcast
  __shared__ int   sInd[NPROP];
  __shared__ unsigned long long sCand[2][4];   // parity double-buffer

  const int tid = threadIdx.x;

  if (blockIdx.x < BATCH) {
    // ================= FPS: 4 waves, one batch per block =================
    const int b    = blockIdx.x;
    const int wave = tid >> 6;
    const int lane = tid & 63;
    const float* xb = xyz + b * NPTS * 3;
    for (int k = tid; k < NPTS; k += 256) {
      sxyz4[k*4+0] = xb[k*3+0];
      sxyz4[k*4+1] = xb[k*3+1];
      sxyz4[k*4+2] = xb[k*3+2];
    }
    __syncthreads();

    // state: k = wave*256 + a*128 + c*64 + lane  (4 points/lane)
    f32x2 px[2], py[2], pz[2], dd[2];
    const int kbase = wave*256 + lane;
#pragma unroll
    for (int a = 0; a < 2; ++a) {
      int k0 = kbase + a*128, k1 = k0 + 64;
      px[a] = (f32x2){sxyz4[k0*4+0], sxyz4[k1*4+0]};
      py[a] = (f32x2){sxyz4[k0*4+1], sxyz4[k1*4+1]};
      pz[a] = (f32x2){sxyz4[k0*4+2], sxyz4[k1*4+2]};
      dd[a] = (f32x2){1e10f, 1e10f};
    }

    int last = 0;
    for (int it = 1; it < NPROP; ++it) {
      float4 lp = *(const float4*)(sxyz4 + last*4);   // broadcast ds_read_b128
      f32x2 vlx = (f32x2){lp.x, lp.x};
      f32x2 vly = (f32x2){lp.y, lp.y};
      f32x2 vlz = (f32x2){lp.z, lp.z};
#pragma unroll
      for (int a = 0; a < 2; ++a) {
        f32x2 dx = px[a] - vlx;
        f32x2 dy = py[a] - vly;
        f32x2 dz = pz[a] - vlz;
        f32x2 d  = dx*dx + dy*dy + dz*dz;   // contract off: mul,mul,mul,add,add
        dd[a] = __builtin_elementwise_min(dd[a], d);
      }
      // per-wave f32 max via validated DPP ladder -> lane 63
      f32x2 mm = __builtin_elementwise_max(dd[0], dd[1]);
      float m = fmaxf(mm[0], mm[1]);
      m = dpp_maxf<0x111>(m);   // row_shr:1
      m = dpp_maxf<0x112>(m);   // row_shr:2
      m = dpp_maxf<0x114>(m);   // row_shr:4
      m = dpp_maxf<0x118>(m);   // row_shr:8
      m = dpp_maxf<0x142>(m);   // row_bcast:15
      m = dpp_maxf<0x143>(m);   // row_bcast:31
      float gmaxw = __builtin_bit_cast(float,
          __builtin_amdgcn_readlane(__builtin_bit_cast(int, m), 63));
      // per-wave index recovery: 4 ballots (j -> k = wave*256 + j*64 + lane)
      unsigned long long msk[4];
      msk[0] = __ballot(dd[0][0] == gmaxw);
      msk[1] = __ballot(dd[0][1] == gmaxw);
      msk[2] = __ballot(dd[1][0] == gmaxw);
      msk[3] = __ballot(dd[1][1] == gmaxw);
      int kl = 0;
#pragma unroll
      for (int j = 3; j >= 0; --j) {
        unsigned long long mj = msk[j];
        if (mj) kl = wave*256 + j*64 + (int)__builtin_ctzll(mj);
      }
      // pack (dist_bits<<32 | 1023-k): bits monotone for d>=0; low field
      // implements first-occurrence argmax tie-break under u64 max
      if (lane == 0)
        sCand[it & 1][wave] =
            ((unsigned long long)__builtin_bit_cast(unsigned, gmaxw) << 32) |
            (unsigned)(1023 - kl);
      __syncthreads();             // parity buffer => one barrier/iter is safe
      unsigned long long c0 = sCand[it & 1][0];
      unsigned long long c1 = sCand[it & 1][1];
      unsigned long long c2 = sCand[it & 1][2];
      unsigned long long c3 = sCand[it & 1][3];
      unsigned long long w01 = c1 > c0 ? c1 : c0;
      unsigned long long w23 = c3 > c2 ? c3 : c2;
      unsigned long long win = w23 > w01 ? w23 : w01;
      last = 1023 - (int)(unsigned)win;   // low 32 bits hold 1023-k exactly
      if (tid == 0) sInd[it] = last;
    }
    if (tid == 0) sInd[0] = 0;
    __syncthreads();

    for (int s = tid; s < NPROP; s += 256) {
      int ind = sInd[s];
      o_inds[b*NPROP + s] = (float)ind;
      float* nx = o_nx + (b*NPROP + s)*3;
      nx[0] = sxyz4[ind*4+0]; nx[1] = sxyz4[ind*4+1]; nx[2] = sxyz4[ind*4+2];
    }
  } else {
    // ================= prep: 224 blocks x 256 threads, grid-stride =========
    const int pid = (blockIdx.x - BATCH) * 256 + tid;    // 0..57343
    const int PSTRIDE = (256 - BATCH) * 256;             // 57344
    // feats -> bf16 (8 floats per step)
    for (int i = pid; i < (BATCH*NPTS*NFEAT)/8; i += PSTRIDE) {
      size_t o = (size_t)i * 8;
      float4 f0 = *(const float4*)(feats + o);
      float4 f1 = *(const float4*)(feats + o + 4);
      u16x8 v;
      v[0]=f2bf(f0.x); v[1]=f2bf(f0.y); v[2]=f2bf(f0.z); v[3]=f2bf(f0.w);
      v[4]=f2bf(f1.x); v[5]=f2bf(f1.y); v[6]=f2bf(f1.z); v[7]=f2bf(f1.w);
      *(u16x8*)(fbf + o) = v;
    }
    // weights + fused bias terms
    for (int id = pid; id < 119424; id += PSTRIDE) {
      if (id < 36864) {                       // w0bt [128][288]
        int n = id / 288, k = id - 288*n;
        float v = 0.f;
        if (k < 256) v = w0[(k+3)*128 + n];
        else if (k < 259) v = w0[(k-256)*128 + n];
        w0bt[id] = f2bf(v);
      } else if (id < 53248) {                // w1bt [128][128]
        int j = id - 36864; int n = j >> 7, k = j & 127;
        w1bt[j] = f2bf(w1[k*128 + n]);
      } else if (id < 69632) {                // w2bt [128][128]
        int j = id - 53248; int n = j >> 7, k = j & 127;
        w2bt[j] = f2bf(w2[k*128 + n]);
      } else if (id < 86016) {                // wfb1 [128][128]
        int j = id - 69632; int n = j >> 7, k = j & 127;
        wfb1[j] = f2bf(wf1[k*128 + n]);
      } else if (id < 102400) {               // wfb2 [128][128]
        int j = id - 86016; int n = j >> 7, k = j & 127;
        wfb2[j] = f2bf(wf2[k*128 + n]);
      } else if (id < 118784) {               // w3pb [128][128] zero-padded
        int j = id - 102400; int n = j >> 7, k = j & 127;
        w3pb[j] = (n < 119) ? f2bf(w3[k*119 + n]) : (unsigned short)0;
      } else if (id < 118912) {
        int c = id - 118784; gb0[c] = fmaf(g0[c], b0[c], be0[c]);
      } else if (id < 119040) {
        int c = id - 118912; gb1[c] = fmaf(g1[c], b1[c], be1[c]);
      } else if (id < 119168) {
        int c = id - 119040; gb2[c] = fmaf(g2[c], b2[c], be2[c]);
      } else if (id < 119296) {
        int c = id - 119168; gbf1[c] = fmaf(gf1[c], bf1[c], bef1[c]);
      } else {
        int c = id - 119296; gbf2[c] = fmaf(gf2[c], bf2[c], bef2[c]);
      }
    }
  }
}

// ---------------------------------------------------------------------------
// Kernel 2a: ball query (in-wave) + grouped MLP via 32x32x16 bf16 MFMA.
// 256-thread blocks = 4 waves; each wave: BQ for its 2 proposals -> LDS,
// then the MLP with a private 8 KiB act slice. Emits bf16 features for the
// MFMA FC head.
// ---------------------------------------------------------------------------
__global__ __launch_bounds__(256) void group_mlp_kernel(
    const float* __restrict__ xyz,
    const unsigned short* __restrict__ fbf,
    const unsigned short* __restrict__ w0bt,
    const unsigned short* __restrict__ w1bt,
    const unsigned short* __restrict__ w2bt,
    const float* __restrict__ g0, const float* __restrict__ gb0,
    const float* __restrict__ g1, const float* __restrict__ gb1,
    const float* __restrict__ g2, const float* __restrict__ gb2,
    const float* __restrict__ onx,
    unsigned short* __restrict__ featbf)
{
  __shared__ __align__(16) unsigned short act[4*4096];   // 32 KiB (8 KiB/wave)
  __shared__ int sIdxAll[4][32];                         // [wave][2 props x 16]

  const int tid  = threadIdx.x;
  const int wave = tid >> 6;
  const int lane = tid & 63;
  const int s  = lane & 31;        // A row (sample) / B-D col bits (channel)
  const int h  = lane >> 5;        // K-half
  const int n0 = s;                // channel lane for B/D
  const int gw = blockIdx.x * 4 + wave;       // global wave id, 0..4095
  const int p  = gw * 2 + (s >> 4);           // this lane's A-row proposal
  const int b  = gw >> 7;                     // batch
  const int samp = s & 15;
  unsigned short* actw = act + wave * 4096;
  int* sIdxW = sIdxAll[wave];

  // ---- in-wave ball query for this wave's 2 proposals (exact fp32 math)
  {
    const float* xb = xyz + b * NPTS * 3;
    const int k0 = lane * 16;
#pragma unroll
    for (int pi = 0; pi < 2; ++pi) {
      const int pp = gw*2 + pi;
      const float qx = onx[pp*3+0];
      const float qy = onx[pp*3+1];
      const float qz = onx[pp*3+2];
      unsigned mask = 0u;
#pragma unroll
      for (int j = 0; j < 16; ++j) {
        int k = k0 + j;
        float dx = __fsub_rn(qx, xb[k*3+0]);
        float dy = __fsub_rn(qy, xb[k*3+1]);
        float dz = __fsub_rn(qz, xb[k*3+2]);
        float d2 = __fadd_rn(__fadd_rn(__fmul_rn(dx,dx), __fmul_rn(dy,dy)), __fmul_rn(dz,dz));
        if (d2 < 0.09f) mask |= (1u << j);
      }
      int cnt  = __popc(mask);
      int incl = cnt;
#pragma unroll
      for (int ofs = 1; ofs < 64; ofs <<= 1) {
        int v = __shfl_up(incl, ofs);
        if (lane >= ofs) incl += v;
      }
      int start = incl - cnt;
      int total = __shfl(incl, 63);
      int fc = mask ? (k0 + __ffs(mask) - 1) : 0x7fffffff;
#pragma unroll
      for (int m = 32; m >= 1; m >>= 1) fc = min(fc, __shfl_xor(fc, m));
      int first = (total > 0) ? fc : (NPTS - 1);
      int* dst = sIdxW + pi*16;
      if (lane >= total && lane < NSAMP) dst[lane] = first;
      int pos = start;
      unsigned mm = mask;
      while (mm && pos < NSAMP) {
        int j = __ffs(mm) - 1; mm &= mm - 1;
        dst[pos] = k0 + j;
        ++pos;
      }
    }
  }
  __syncthreads();   // all 4 waves reach this; also orders sIdx writes

  const int idx = sIdxW[(s>>4)*16 + samp];
  const unsigned short* arow = fbf + ((size_t)(b*NPTS + idx) << 8);

  // gxyz A-fragment for kstep 16 (k=256..258 live in h==0 lanes)
  bf16x8 agx = (bf16x8){0,0,0,0,0,0,0,0};
  if (h == 0) {
    const float* pp = xyz + (size_t)(b*NPTS + idx)*3;
    agx[0] = (short)f2bf((pp[0] - onx[p*3+0]) * (1.0f/0.3f));
    agx[1] = (short)f2bf((pp[1] - onx[p*3+1]) * (1.0f/0.3f));
    agx[2] = (short)f2bf((pp[2] - onx[p*3+2]) * (1.0f/0.3f));
  }

  f32x16 acc[4];
#pragma unroll
  for (int nt = 0; nt < 4; ++nt) acc[nt] = (f32x16)(0.f);

  // ---- layer 0: K = 259 (ksteps 0..15 feats, 16 = gxyz; zero kstep skipped)
#pragma unroll 4
  for (int ks = 0; ks < 16; ++ks) {
    bf16x8 a = *(const bf16x8*)(arow + ks*16 + h*8);
    const unsigned short* wp = w0bt + (size_t)n0*288 + ks*16 + h*8;
#pragma unroll
    for (int nt = 0; nt < 4; ++nt) {
      bf16x8 bb = *(const bf16x8*)(wp + (size_t)nt*32*288);
      acc[nt] = __builtin_amdgcn_mfma_f32_32x32x16_bf16(a, bb, acc[nt], 0, 0, 0);
    }
  }
  {
    const unsigned short* wp = w0bt + (size_t)n0*288 + 256 + h*8;
#pragma unroll
    for (int nt = 0; nt < 4; ++nt) {
      bf16x8 bb = *(const bf16x8*)(wp + (size_t)nt*32*288);
      acc[nt] = __builtin_amdgcn_mfma_f32_32x32x16_bf16(agx, bb, acc[nt], 0, 0, 0);
    }
  }
  // act0 -> LDS (relu(g*x+gb)), swizzled layout
#pragma unroll
  for (int nt = 0; nt < 4; ++nt) {
    int c = nt*32 + n0;
    int gch = c >> 3;
    float gg = g0[c], gv = gb0[c];
    int base = gch*256 + (c & 7);
#pragma unroll
    for (int r = 0; r < 16; ++r) {
      int srow = (r & 3) + 8*(r >> 2) + 4*h;
      float v = fmaxf(fmaf(gg, acc[nt][r], gv), 0.f);
      actw[base + ((srow + 2*gch) & 31)*8] = f2bf(v);
    }
  }
  __syncthreads();

  // ---- layer 1: K = 128
#pragma unroll
  for (int nt = 0; nt < 4; ++nt) acc[nt] = (f32x16)(0.f);
#pragma unroll 4
  for (int ks = 0; ks < 8; ++ks) {
    int g = ks*2 + h;
    bf16x8 a = *(const bf16x8*)(actw + g*256 + ((s + 2*g) & 31)*8);
    const unsigned short* wp = w1bt + (size_t)n0*128 + ks*16 + h*8;
#pragma unroll
    for (int nt = 0; nt < 4; ++nt) {
      bf16x8 bb = *(const bf16x8*)(wp + (size_t)nt*32*128);
      acc[nt] = __builtin_amdgcn_mfma_f32_32x32x16_bf16(a, bb, acc[nt], 0, 0, 0);
    }
  }
  __syncthreads();
#pragma unroll
  for (int nt = 0; nt < 4; ++nt) {
    int c = nt*32 + n0;
    int gch = c >> 3;
    float gg = g1[c], gv = gb1[c];
    int base = gch*256 + (c & 7);
#pragma unroll
    for (int r = 0; r < 16; ++r) {
      int srow = (r & 3) + 8*(r >> 2) + 4*h;
      float v = fmaxf(fmaf(gg, acc[nt][r], gv), 0.f);
      actw[base + ((srow + 2*gch) & 31)*8] = f2bf(v);
    }
  }
  __syncthreads();

  // ---- layer 2: K = 128, fused maxpool over each proposal's 16 samples
#pragma unroll
  for (int nt = 0; nt < 4; ++nt) acc[nt] = (f32x16)(0.f);
#pragma unroll 4
  for (int ks = 0; ks < 8; ++ks) {
    int g = ks*2 + h;
    bf16x8 a = *(const bf16x8*)(actw + g*256 + ((s + 2*g) & 31)*8);
    const unsigned short* wp = w2bt + (size_t)n0*128 + ks*16 + h*8;
#pragma unroll
    for (int nt = 0; nt < 4; ++nt) {
      bf16x8 bb = *(const bf16x8*)(wp + (size_t)nt*32*128);
      acc[nt] = __builtin_amdgcn_mfma_f32_32x32x16_bf16(a, bb, acc[nt], 0, 0, 0);
    }
  }
#pragma unroll
  for (int nt = 0; nt < 4; ++nt) {
    int c = nt*32 + n0;
    float gg = g2[c], gv = gb2[c];
    float m0 = 0.f, m1 = 0.f;   // relu => max >= 0
#pragma unroll
    for (int r = 0; r < 8; ++r)
      m0 = fmaxf(m0, fmaxf(fmaf(gg, acc[nt][r], gv), 0.f));       // rows 0..15  (prop lo)
#pragma unroll
    for (int r = 8; r < 16; ++r)
      m1 = fmaxf(m1, fmaxf(fmaf(gg, acc[nt][r], gv), 0.f));       // rows 16..31 (prop hi)
    m0 = fmaxf(m0, __shfl_xor(m0, 32));
    m1 = fmaxf(m1, __shfl_xor(m1, 32));
    float vout = h ? m1 : m0;
    featbf[(size_t)(gw*2 + h)*128 + c] = f2bf(vout);
  }
}

// ---------------------------------------------------------------------------
// Kernel 2b: FC head via 32x32x16 bf16 MFMA — one wave per 32 proposals,
// barrier-free (private LDS slice; DS ops are in-order within a wave).
// Fragment/swizzle code identical to group_mlp layers 1/2 (validated).
// ---------------------------------------------------------------------------
__global__ __launch_bounds__(64) void fc_head_kernel(
    const unsigned short* __restrict__ featbf,
    const float* __restrict__ onx,
    const float* __restrict__ msize,
    const unsigned short* __restrict__ wfb1,
    const float* __restrict__ gf1, const float* __restrict__ gbf1,
    const unsigned short* __restrict__ wfb2,
    const float* __restrict__ gf2, const float* __restrict__ gbf2,
    const unsigned short* __restrict__ w3pb,
    const float* __restrict__ b3,
    float* __restrict__ out)
{
  __shared__ __align__(16) unsigned short actw[4096];   // 8 KiB, one wave
  const int lane = threadIdx.x;
  const int s  = lane & 31;        // A row (proposal) / B-D col bits
  const int h  = lane >> 5;        // K-half
  const int n0 = s;
  const int p0 = blockIdx.x * 32;  // this wave's 32 proposals

  f32x16 acc[4];

  // ---- FC1 (relu6): A = featbf rows p0..p0+31, K = 128
#pragma unroll
  for (int nt = 0; nt < 4; ++nt) acc[nt] = (f32x16)(0.f);
#pragma unroll
  for (int ks = 0; ks < 8; ++ks) {
    bf16x8 a = *(const bf16x8*)(featbf + (((size_t)(p0 + s)) << 7) + ks*16 + h*8);
    const unsigned short* wp = wfb1 + (size_t)n0*128 + ks*16 + h*8;
#pragma unroll
    for (int nt = 0; nt < 4; ++nt) {
      bf16x8 bb = *(const bf16x8*)(wp + (size_t)nt*32*128);
      acc[nt] = __builtin_amdgcn_mfma_f32_32x32x16_bf16(a, bb, acc[nt], 0, 0, 0);
    }
  }
#pragma unroll
  for (int nt = 0; nt < 4; ++nt) {
    int c = nt*32 + n0;
    int gch = c >> 3;
    float gg = gf1[c], gv = gbf1[c];
    int base = gch*256 + (c & 7);
#pragma unroll
    for (int r = 0; r < 16; ++r) {
      int srow = (r & 3) + 8*(r >> 2) + 4*h;
      float v = fminf(fmaxf(fmaf(gg, acc[nt][r], gv), 0.f), 6.f);
      actw[base + ((srow + 2*gch) & 31)*8] = f2bf(v);
    }
  }

  // ---- FC2 (relu6): K = 128 from LDS
#pragma unroll
  for (int nt = 0; nt < 4; ++nt) acc[nt] = (f32x16)(0.f);
#pragma unroll
  for (int ks = 0; ks < 8; ++ks) {
    int g = ks*2 + h;
    bf16x8 a = *(const bf16x8*)(actw + g*256 + ((s + 2*g) & 31)*8);
    const unsigned short* wp = wfb2 + (size_t)n0*128 + ks*16 + h*8;
#pragma unroll
    for (int nt = 0; nt < 4; ++nt) {
      bf16x8 bb = *(const bf16x8*)(wp + (size_t)nt*32*128);
      acc[nt] = __builtin_amdgcn_mfma_f32_32x32x16_bf16(a, bb, acc[nt], 0, 0, 0);
    }
  }
#pragma unroll
  for (int nt = 0; nt < 4; ++nt) {
    int c = nt*32 + n0;
    int gch = c >> 3;
    float gg = gf2[c], gv = gbf2[c];
    int base = gch*256 + (c & 7);
#pragma unroll
    for (int r = 0; r < 16; ++r) {
      int srow = (r & 3) + 8*(r >> 2) + 4*h;
      float v = fminf(fmaxf(fmaf(gg, acc[nt][r], gv), 0.f), 6.f);
      actw[base + ((srow + 2*gch) & 31)*8] = f2bf(v);
    }
  }

  // ---- FC3: K = 128, scatter with transforms
#pragma unroll
  for (int nt = 0; nt < 4; ++nt) acc[nt] = (f32x16)(0.f);
#pragma unroll
  for (int ks = 0; ks < 8; ++ks) {
    int g = ks*2 + h;
    bf16x8 a = *(const bf16x8*)(actw + g*256 + ((s + 2*g) & 31)*8);
    const unsigned short* wp = w3pb + (size_t)n0*128 + ks*16 + h*8;
#pragma unroll
    for (int nt = 0; nt < 4; ++nt) {
      bf16x8 bb = *(const bf16x8*)(wp + (size_t)nt*32*128);
      acc[nt] = __builtin_amdgcn_mfma_f32_32x32x16_bf16(a, bb, acc[nt], 0, 0, 0);
    }
  }
  const float HRC = (float)(3.14159265359 / 12.0);
#pragma unroll
  for (int nt = 0; nt < 4; ++nt) {
    int c = nt*32 + n0;
    if (c >= 119) continue;
    float b3v = b3[c];
#pragma unroll
    for (int r = 0; r < 16; ++r) {
      int srow = (r & 3) + 8*(r >> 2) + 4*h;
      int bp = p0 + srow;
      float v = acc[nt][r] + b3v;
      if (c < 3) {
        out[O_CENTER + bp*3 + c] = onx[bp*3 + c] + v;
      } else if (c < 5) {
        out[O_OBJ + bp*2 + (c-3)] = v;
      } else if (c < 17) {
        out[O_HS + bp*12 + (c-5)] = v;
      } else if (c < 35) {
        out[O_SS + bp*18 + (c-17)] = v;
      } else if (c < 47) {
        int a2 = c - 35;
        out[O_HRN + bp*12 + a2] = v;
        out[O_HR  + bp*12 + a2] = v * HRC;
      } else if (c < 101) {
        int a2 = c - 47;
        out[O_SRN + bp*54 + a2] = v;
        out[O_SR  + bp*54 + a2] = v * msize[a2];
      } else {
        int a2 = c - 101;
        out[O_SEM + bp*18 + a2] = v;
      }
    }
  }
}

// ---------------------------------------------------------------------------
extern "C" void kernel_launch(void* const* d_in, const int* in_sizes, int n_in,
                              void* d_out, int out_size, void* d_ws, size_t ws_size,
                              hipStream_t stream) {
  (void)in_sizes; (void)n_in; (void)out_size; (void)ws_size;
  const float* xyz   = (const float*)d_in[0];
  const float* feats = (const float*)d_in[1];
  const float* msize = (const float*)d_in[2];
  const float* w0  = (const float*)d_in[3];
  const float* b0  = (const float*)d_in[4];
  const float* g0  = (const float*)d_in[5];
  const float* be0 = (const float*)d_in[6];
  const float* w1  = (const float*)d_in[7];
  const float* b1  = (const float*)d_in[8];
  const float* g1  = (const float*)d_in[9];
  const float* be1 = (const float*)d_in[10];
  const float* w2  = (const float*)d_in[11];
  const float* b2  = (const float*)d_in[12];
  const float* g2  = (const float*)d_in[13];
  const float* be2 = (const float*)d_in[14];
  const float* wf1  = (const float*)d_in[15];
  const float* bf1  = (const float*)d_in[16];
  const float* gf1  = (const float*)d_in[17];
  const float* bef1 = (const float*)d_in[18];
  const float* wf2  = (const float*)d_in[19];
  const float* bf2  = (const float*)d_in[20];
  const float* gf2  = (const float*)d_in[21];
  const float* bef2 = (const float*)d_in[22];
  const float* w3 = (const float*)d_in[23];
  const float* b3 = (const float*)d_in[24];

  float* out = (float*)d_out;

  // workspace layout (bytes) — stays within the previously-used footprint
  char* wsb = (char*)d_ws;
  unsigned short* wfb1   = (unsigned short*)(wsb + 0);          //  32 KiB
  unsigned short* wfb2   = (unsigned short*)(wsb + 32768);      //  32 KiB
  unsigned short* w3pb   = (unsigned short*)(wsb + 65536);      //  32 KiB
  float*          gbf1   = (float*)         (wsb + 98304);      //  512 B
  float*          gbf2   = (float*)         (wsb + 98816);      //  512 B
  unsigned short* fbf    = (unsigned short*)(wsb + 524288);     //  16 MiB
  unsigned short* featbf = (unsigned short*)(wsb + 17301504);   //   2 MiB
  unsigned short* w0bt   = (unsigned short*)(wsb + 21495808);   //  72 KiB
  unsigned short* w1bt   = (unsigned short*)(wsb + 21569536);   //  32 KiB
  unsigned short* w2bt   = (unsigned short*)(wsb + 21602304);   //  32 KiB
  float*          gb0    = (float*)         (wsb + 21635072);   //  512 B
  float*          gb1    = (float*)         (wsb + 21635584);   //  512 B
  float*          gb2    = (float*)         (wsb + 21636096);   //  512 B

  fps_prep_kernel<<<256, 256, 0, stream>>>(
      xyz, feats, w0, w1, w2, w3,
      b0, g0, be0, b1, g1, be1, b2, g2, be2,
      wf1, bf1, gf1, bef1, wf2, bf2, gf2, bef2,
      fbf, w0bt, w1bt, w2bt, wfb1, wfb2, w3pb,
      gb0, gb1, gb2, gbf1, gbf2,
      out + O_NX, out + O_INDS);
  group_mlp_kernel<<<(BATCH*NPROP)/8, 256, 0, stream>>>(
      xyz, fbf, w0bt, w1bt, w2bt,
      g0, gb0, g1, gb1, g2, gb2,
      out + O_NX, featbf);
  fc_head_kernel<<<(BATCH*NPROP)/32, 64, 0, stream>>>(
      featbf, out + O_NX, msize,
      wfb1, gf1, gbf1, wfb2, gf2, gbf2, w3pb, b3, out);
}

// Round 11
// 305.185 us; speedup vs baseline: 1.0743x; 1.0011x over previous
//
#include <hip/hip_runtime.h>

#define BATCH 32
#define NPTS  1024
#define NFEAT 256
#define NPROP 256
#define NSAMP 16

// flat output offsets (floats), in reference tuple order
#define O_OBJ    0
#define O_CENTER 16384
#define O_HS     40960
#define O_HRN    139264
#define O_HR     237568
#define O_SS     335872
#define O_SRN    483328
#define O_SR     925696
#define O_SEM    1368064
#define O_NX     1515520
#define O_INDS   1540096

typedef __attribute__((ext_vector_type(8))) short bf16x8;
typedef __attribute__((ext_vector_type(8))) unsigned short u16x8;
typedef __attribute__((ext_vector_type(2))) float f32x2;
typedef __attribute__((ext_vector_type(4))) float f32x4;
typedef __attribute__((ext_vector_type(16))) float f32x16;

__device__ __forceinline__ unsigned short f2bf(float f) {
  unsigned u = __builtin_bit_cast(unsigned, f);
  u += 0x7fffu + ((u >> 16) & 1u);   // RNE to bf16
  return (unsigned short)(u >> 16);
}

// single-op DPP f32 max step (ctrl pattern hardware-validated R3-R6 + R1)
template<int CTRL>
__device__ __forceinline__ float dpp_maxf(float v) {
  int x = __builtin_amdgcn_update_dpp(__builtin_bit_cast(int, v),
          __builtin_bit_cast(int, v), CTRL, 0xf, 0xf, false);
  return fmaxf(v, __builtin_bit_cast(float, x));
}

// ---------------------------------------------------------------------------
// Kernel 1: blocks 0..31 = FPS for batch b (4 waves, 4 pts/lane); blocks
// 32..255 = grid-stride prep (streams concurrently; barriers block-scoped).
// FPS per iter (validated primitives only): broadcast ds_read_b128, packed
// dist update, f32 DPP ladder -> wave max, readlane, 4 ballots + scan ->
// per-wave min-index; lane0 packs (distbits<<32 | 1023-k) to a parity LDS
// slot; one __syncthreads; scalar u64 compares pick the winner.
// Exact fp32 math (contract off); tie-break == jnp.argmax first-occurrence.
// NOTE (R8 post-mortem): single-wave 16pts/lane variants are allocator-
// limited to VGPR=40 (LDS remat on the serial chain, ~120us) regardless of
// __launch_bounds__ or asm pins; this 4-wave structure is the measured
// optimum at ~103us / 985 cyc/iter (R4/R9).
// ---------------------------------------------------------------------------
__global__ __launch_bounds__(256) void fps_prep_kernel(
    const float* __restrict__ xyz,
    const float* __restrict__ feats,
    const float* __restrict__ w0, const float* __restrict__ w1,
    const float* __restrict__ w2, const float* __restrict__ w3,
    const float* __restrict__ b0, const float* __restrict__ g0, const float* __restrict__ be0,
    const float* __restrict__ b1, const float* __restrict__ g1, const float* __restrict__ be1,
    const float* __restrict__ b2, const float* __restrict__ g2, const float* __restrict__ be2,
    const float* __restrict__ wf1, const float* __restrict__ bf1,
    const float* __restrict__ gf1, const float* __restrict__ bef1,
    const float* __restrict__ wf2, const float* __restrict__ bf2,
    const float* __restrict__ gf2, const float* __restrict__ bef2,
    unsigned short* __restrict__ fbf,
    unsigned short* __restrict__ w0bt, unsigned short* __restrict__ w1bt,
    unsigned short* __restrict__ w2bt,
    unsigned short* __restrict__ wfb1, unsigned short* __restrict__ wfb2,
    unsigned short* __restrict__ w3pb,
    float* __restrict__ gb0, float* __restrict__ gb1, float* __restrict__ gb2,
    float* __restrict__ gbf1, float* __restrict__ gbf2,
    float* __restrict__ o_nx,
    float* __restrict__ o_inds)
{
#pragma clang fp contract(off)
  __shared__ float sxyz4[NPTS*4];          // [1024][4] for b128 broadcast
  __shared__ int   sInd[NPROP];
  __shared__ unsigned long long sCand[2][4];   // parity double-buffer

  const int tid = threadIdx.x;

  if (blockIdx.x < BATCH) {
    // ================= FPS: 4 waves, one batch per block =================
    const int b    = blockIdx.x;
    const int wave = tid >> 6;
    const int lane = tid & 63;
    const float* xb = xyz + b * NPTS * 3;
    for (int k = tid; k < NPTS; k += 256) {
      sxyz4[k*4+0] = xb[k*3+0];
      sxyz4[k*4+1] = xb[k*3+1];
      sxyz4[k*4+2] = xb[k*3+2];
    }
    __syncthreads();

    // state: k = wave*256 + a*128 + c*64 + lane  (4 points/lane)
    f32x2 px[2], py[2], pz[2], dd[2];
    const int kbase = wave*256 + lane;
#pragma unroll
    for (int a = 0; a < 2; ++a) {
      int k0 = kbase + a*128, k1 = k0 + 64;
      px[a] = (f32x2){sxyz4[k0*4+0], sxyz4[k1*4+0]};
      py[a] = (f32x2){sxyz4[k0*4+1], sxyz4[k1*4+1]};
      pz[a] = (f32x2){sxyz4[k0*4+2], sxyz4[k1*4+2]};
      dd[a] = (f32x2){1e10f, 1e10f};
    }

    int last = 0;
    for (int it = 1; it < NPROP; ++it) {
      float4 lp = *(const float4*)(sxyz4 + last*4);   // broadcast ds_read_b128
      f32x2 vlx = (f32x2){lp.x, lp.x};
      f32x2 vly = (f32x2){lp.y, lp.y};
      f32x2 vlz = (f32x2){lp.z, lp.z};
#pragma unroll
      for (int a = 0; a < 2; ++a) {
        f32x2 dx = px[a] - vlx;
        f32x2 dy = py[a] - vly;
        f32x2 dz = pz[a] - vlz;
        f32x2 d  = dx*dx + dy*dy + dz*dz;   // contract off: mul,mul,mul,add,add
        dd[a] = __builtin_elementwise_min(dd[a], d);
      }
      // per-wave f32 max via validated DPP ladder -> lane 63
      f32x2 mm = __builtin_elementwise_max(dd[0], dd[1]);
      float m = fmaxf(mm[0], mm[1]);
      m = dpp_maxf<0x111>(m);   // row_shr:1
      m = dpp_maxf<0x112>(m);   // row_shr:2
      m = dpp_maxf<0x114>(m);   // row_shr:4
      m = dpp_maxf<0x118>(m);   // row_shr:8
      m = dpp_maxf<0x142>(m);   // row_bcast:15
      m = dpp_maxf<0x143>(m);   // row_bcast:31
      float gmaxw = __builtin_bit_cast(float,
          __builtin_amdgcn_readlane(__builtin_bit_cast(int, m), 63));
      // per-wave index recovery: 4 ballots (j -> k = wave*256 + j*64 + lane)
      unsigned long long msk[4];
      msk[0] = __ballot(dd[0][0] == gmaxw);
      msk[1] = __ballot(dd[0][1] == gmaxw);
      msk[2] = __ballot(dd[1][0] == gmaxw);
      msk[3] = __ballot(dd[1][1] == gmaxw);
      int kl = 0;
#pragma unroll
      for (int j = 3; j >= 0; --j) {
        unsigned long long mj = msk[j];
        if (mj) kl = wave*256 + j*64 + (int)__builtin_ctzll(mj);
      }
      // pack (dist_bits<<32 | 1023-k): bits monotone for d>=0; low field
      // implements first-occurrence argmax tie-break under u64 max
      if (lane == 0)
        sCand[it & 1][wave] =
            ((unsigned long long)__builtin_bit_cast(unsigned, gmaxw) << 32) |
            (unsigned)(1023 - kl);
      __syncthreads();             // parity buffer => one barrier/iter is safe
      unsigned long long c0 = sCand[it & 1][0];
      unsigned long long c1 = sCand[it & 1][1];
      unsigned long long c2 = sCand[it & 1][2];
      unsigned long long c3 = sCand[it & 1][3];
      unsigned long long w01 = c1 > c0 ? c1 : c0;
      unsigned long long w23 = c3 > c2 ? c3 : c2;
      unsigned long long win = w23 > w01 ? w23 : w01;
      last = 1023 - (int)(unsigned)win;   // low 32 bits hold 1023-k exactly
      if (tid == 0) sInd[it] = last;
    }
    if (tid == 0) sInd[0] = 0;
    __syncthreads();

    for (int s = tid; s < NPROP; s += 256) {
      int ind = sInd[s];
      o_inds[b*NPROP + s] = (float)ind;
      float* nx = o_nx + (b*NPROP + s)*3;
      nx[0] = sxyz4[ind*4+0]; nx[1] = sxyz4[ind*4+1]; nx[2] = sxyz4[ind*4+2];
    }
  } else {
    // ================= prep: 224 blocks x 256 threads, grid-stride =========
    const int pid = (blockIdx.x - BATCH) * 256 + tid;    // 0..57343
    const int PSTRIDE = (256 - BATCH) * 256;             // 57344
    // feats -> bf16 (8 floats per step)
    for (int i = pid; i < (BATCH*NPTS*NFEAT)/8; i += PSTRIDE) {
      size_t o = (size_t)i * 8;
      float4 f0 = *(const float4*)(feats + o);
      float4 f1 = *(const float4*)(feats + o + 4);
      u16x8 v;
      v[0]=f2bf(f0.x); v[1]=f2bf(f0.y); v[2]=f2bf(f0.z); v[3]=f2bf(f0.w);
      v[4]=f2bf(f1.x); v[5]=f2bf(f1.y); v[6]=f2bf(f1.z); v[7]=f2bf(f1.w);
      *(u16x8*)(fbf + o) = v;
    }
    // weights + fused bias terms
    for (int id = pid; id < 119424; id += PSTRIDE) {
      if (id < 36864) {                       // w0bt [128][288]
        int n = id / 288, k = id - 288*n;
        float v = 0.f;
        if (k < 256) v = w0[(k+3)*128 + n];
        else if (k < 259) v = w0[(k-256)*128 + n];
        w0bt[id] = f2bf(v);
      } else if (id < 53248) {                // w1bt [128][128]
        int j = id - 36864; int n = j >> 7, k = j & 127;
        w1bt[j] = f2bf(w1[k*128 + n]);
      } else if (id < 69632) {                // w2bt [128][128]
        int j = id - 53248; int n = j >> 7, k = j & 127;
        w2bt[j] = f2bf(w2[k*128 + n]);
      } else if (id < 86016) {                // wfb1 [128][128]
        int j = id - 69632; int n = j >> 7, k = j & 127;
        wfb1[j] = f2bf(wf1[k*128 + n]);
      } else if (id < 102400) {               // wfb2 [128][128]
        int j = id - 86016; int n = j >> 7, k = j & 127;
        wfb2[j] = f2bf(wf2[k*128 + n]);
      } else if (id < 118784) {               // w3pb [128][128] zero-padded
        int j = id - 102400; int n = j >> 7, k = j & 127;
        w3pb[j] = (n < 119) ? f2bf(w3[k*119 + n]) : (unsigned short)0;
      } else if (id < 118912) {
        int c = id - 118784; gb0[c] = fmaf(g0[c], b0[c], be0[c]);
      } else if (id < 119040) {
        int c = id - 118912; gb1[c] = fmaf(g1[c], b1[c], be1[c]);
      } else if (id < 119168) {
        int c = id - 119040; gb2[c] = fmaf(g2[c], b2[c], be2[c]);
      } else if (id < 119296) {
        int c = id - 119168; gbf1[c] = fmaf(gf1[c], bf1[c], bef1[c]);
      } else {
        int c = id - 119296; gbf2[c] = fmaf(gf2[c], bf2[c], bef2[c]);
      }
    }
  }
}

// ---------------------------------------------------------------------------
// Kernel 2a: ball query (in-wave) + grouped MLP via 32x32x16 bf16 MFMA.
// 256-thread blocks = 4 waves; each wave: BQ for its 2 proposals -> LDS,
// then the MLP with a private 8 KiB act slice. Emits bf16 features for the
// MFMA FC head.
// R10: BQ loads vectorized — each lane's 16 points are 48 consecutive
// floats = 12 f32x4 loads shared by BOTH proposals (was 96 scalar loads).
// Distance math sequence unchanged (bit-exact).
// ---------------------------------------------------------------------------
__global__ __launch_bounds__(256) void group_mlp_kernel(
    const float* __restrict__ xyz,
    const unsigned short* __restrict__ fbf,
    const unsigned short* __restrict__ w0bt,
    const unsigned short* __restrict__ w1bt,
    const unsigned short* __restrict__ w2bt,
    const float* __restrict__ g0, const float* __restrict__ gb0,
    const float* __restrict__ g1, const float* __restrict__ gb1,
    const float* __restrict__ g2, const float* __restrict__ gb2,
    const float* __restrict__ onx,
    unsigned short* __restrict__ featbf)
{
  __shared__ __align__(16) unsigned short act[4*4096];   // 32 KiB (8 KiB/wave)
  __shared__ int sIdxAll[4][32];                         // [wave][2 props x 16]

  const int tid  = threadIdx.x;
  const int wave = tid >> 6;
  const int lane = tid & 63;
  const int s  = lane & 31;        // A row (sample) / B-D col bits (channel)
  const int h  = lane >> 5;        // K-half
  const int n0 = s;                // channel lane for B/D
  const int gw = blockIdx.x * 4 + wave;       // global wave id, 0..4095
  const int p  = gw * 2 + (s >> 4);           // this lane's A-row proposal
  const int b  = gw >> 7;                     // batch
  const int samp = s & 15;
  unsigned short* actw = act + wave * 4096;
  int* sIdxW = sIdxAll[wave];

  // ---- in-wave ball query for this wave's 2 proposals (exact fp32 math)
  {
    const float* xb = xyz + b * NPTS * 3;
    const int k0 = lane * 16;
    const float q0x = onx[(gw*2+0)*3+0];
    const float q0y = onx[(gw*2+0)*3+1];
    const float q0z = onx[(gw*2+0)*3+2];
    const float q1x = onx[(gw*2+1)*3+0];
    const float q1y = onx[(gw*2+1)*3+1];
    const float q1z = onx[(gw*2+1)*3+2];
    unsigned masks[2] = {0u, 0u};
#pragma unroll
    for (int ch = 0; ch < 4; ++ch) {
      const float* pbase = xb + (size_t)k0*3 + ch*12;   // 16B-aligned
      f32x4 f0 = *(const f32x4*)(pbase);
      f32x4 f1 = *(const f32x4*)(pbase + 4);
      f32x4 f2 = *(const f32x4*)(pbase + 8);
      // 4 points per chunk: compile-time component extraction
      float xs[4] = {f0[0], f0[3], f1[2], f2[1]};
      float ys[4] = {f0[1], f1[0], f1[3], f2[2]};
      float zs[4] = {f0[2], f1[1], f2[0], f2[3]};
#pragma unroll
      for (int jj = 0; jj < 4; ++jj) {
        int j = ch*4 + jj;
        {
          float dx = __fsub_rn(q0x, xs[jj]);
          float dy = __fsub_rn(q0y, ys[jj]);
          float dz = __fsub_rn(q0z, zs[jj]);
          float d2 = __fadd_rn(__fadd_rn(__fmul_rn(dx,dx), __fmul_rn(dy,dy)), __fmul_rn(dz,dz));
          if (d2 < 0.09f) masks[0] |= (1u << j);
        }
        {
          float dx = __fsub_rn(q1x, xs[jj]);
          float dy = __fsub_rn(q1y, ys[jj]);
          float dz = __fsub_rn(q1z, zs[jj]);
          float d2 = __fadd_rn(__fadd_rn(__fmul_rn(dx,dx), __fmul_rn(dy,dy)), __fmul_rn(dz,dz));
          if (d2 < 0.09f) masks[1] |= (1u << j);
        }
      }
    }
#pragma unroll
    for (int pi = 0; pi < 2; ++pi) {
      unsigned mask = masks[pi];
      int cnt  = __popc(mask);
      int incl = cnt;
#pragma unroll
      for (int ofs = 1; ofs < 64; ofs <<= 1) {
        int v = __shfl_up(incl, ofs);
        if (lane >= ofs) incl += v;
      }
      int start = incl - cnt;
      int total = __shfl(incl, 63);
      int fc = mask ? (k0 + __ffs(mask) - 1) : 0x7fffffff;
#pragma unroll
      for (int m = 32; m >= 1; m >>= 1) fc = min(fc, __shfl_xor(fc, m));
      int first = (total > 0) ? fc : (NPTS - 1);
      int* dst = sIdxW + pi*16;
      if (lane >= total && lane < NSAMP) dst[lane] = first;
      int pos = start;
      unsigned mm = mask;
      while (mm && pos < NSAMP) {
        int j = __ffs(mm) - 1; mm &= mm - 1;
        dst[pos] = k0 + j;
        ++pos;
      }
    }
  }
  __syncthreads();   // all 4 waves reach this; also orders sIdx writes

  const int idx = sIdxW[(s>>4)*16 + samp];
  const unsigned short* arow = fbf + ((size_t)(b*NPTS + idx) << 8);

  // gxyz A-fragment for kstep 16 (k=256..258 live in h==0 lanes)
  bf16x8 agx = (bf16x8){0,0,0,0,0,0,0,0};
  if (h == 0) {
    const float* pp = xyz + (size_t)(b*NPTS + idx)*3;
    agx[0] = (short)f2bf((pp[0] - onx[p*3+0]) * (1.0f/0.3f));
    agx[1] = (short)f2bf((pp[1] - onx[p*3+1]) * (1.0f/0.3f));
    agx[2] = (short)f2bf((pp[2] - onx[p*3+2]) * (1.0f/0.3f));
  }

  f32x16 acc[4];
#pragma unroll
  for (int nt = 0; nt < 4; ++nt) acc[nt] = (f32x16)(0.f);

  // ---- layer 0: K = 259 (ksteps 0..15 feats, 16 = gxyz; zero kstep skipped)
#pragma unroll 4
  for (int ks = 0; ks < 16; ++ks) {
    bf16x8 a = *(const bf16x8*)(arow + ks*16 + h*8);
    const unsigned short* wp = w0bt + (size_t)n0*288 + ks*16 + h*8;
#pragma unroll
    for (int nt = 0; nt < 4; ++nt) {
      bf16x8 bb = *(const bf16x8*)(wp + (size_t)nt*32*288);
      acc[nt] = __builtin_amdgcn_mfma_f32_32x32x16_bf16(a, bb, acc[nt], 0, 0, 0);
    }
  }
  {
    const unsigned short* wp = w0bt + (size_t)n0*288 + 256 + h*8;
#pragma unroll
    for (int nt = 0; nt < 4; ++nt) {
      bf16x8 bb = *(const bf16x8*)(wp + (size_t)nt*32*288);
      acc[nt] = __builtin_amdgcn_mfma_f32_32x32x16_bf16(agx, bb, acc[nt], 0, 0, 0);
    }
  }
  // act0 -> LDS (relu(g*x+gb)), swizzled layout
#pragma unroll
  for (int nt = 0; nt < 4; ++nt) {
    int c = nt*32 + n0;
    int gch = c >> 3;
    float gg = g0[c], gv = gb0[c];
    int base = gch*256 + (c & 7);
#pragma unroll
    for (int r = 0; r < 16; ++r) {
      int srow = (r & 3) + 8*(r >> 2) + 4*h;
      float v = fmaxf(fmaf(gg, acc[nt][r], gv), 0.f);
      actw[base + ((srow + 2*gch) & 31)*8] = f2bf(v);
    }
  }
  __syncthreads();

  // ---- layer 1: K = 128
#pragma unroll
  for (int nt = 0; nt < 4; ++nt) acc[nt] = (f32x16)(0.f);
#pragma unroll 4
  for (int ks = 0; ks < 8; ++ks) {
    int g = ks*2 + h;
    bf16x8 a = *(const bf16x8*)(actw + g*256 + ((s + 2*g) & 31)*8);
    const unsigned short* wp = w1bt + (size_t)n0*128 + ks*16 + h*8;
#pragma unroll
    for (int nt = 0; nt < 4; ++nt) {
      bf16x8 bb = *(const bf16x8*)(wp + (size_t)nt*32*128);
      acc[nt] = __builtin_amdgcn_mfma_f32_32x32x16_bf16(a, bb, acc[nt], 0, 0, 0);
    }
  }
  __syncthreads();
#pragma unroll
  for (int nt = 0; nt < 4; ++nt) {
    int c = nt*32 + n0;
    int gch = c >> 3;
    float gg = g1[c], gv = gb1[c];
    int base = gch*256 + (c & 7);
#pragma unroll
    for (int r = 0; r < 16; ++r) {
      int srow = (r & 3) + 8*(r >> 2) + 4*h;
      float v = fmaxf(fmaf(gg, acc[nt][r], gv), 0.f);
      actw[base + ((srow + 2*gch) & 31)*8] = f2bf(v);
    }
  }
  __syncthreads();

  // ---- layer 2: K = 128, fused maxpool over each proposal's 16 samples
#pragma unroll
  for (int nt = 0; nt < 4; ++nt) acc[nt] = (f32x16)(0.f);
#pragma unroll 4
  for (int ks = 0; ks < 8; ++ks) {
    int g = ks*2 + h;
    bf16x8 a = *(const bf16x8*)(actw + g*256 + ((s + 2*g) & 31)*8);
    const unsigned short* wp = w2bt + (size_t)n0*128 + ks*16 + h*8;
#pragma unroll
    for (int nt = 0; nt < 4; ++nt) {
      bf16x8 bb = *(const bf16x8*)(wp + (size_t)nt*32*128);
      acc[nt] = __builtin_amdgcn_mfma_f32_32x32x16_bf16(a, bb, acc[nt], 0, 0, 0);
    }
  }
#pragma unroll
  for (int nt = 0; nt < 4; ++nt) {
    int c = nt*32 + n0;
    float gg = g2[c], gv = gb2[c];
    float m0 = 0.f, m1 = 0.f;   // relu => max >= 0
#pragma unroll
    for (int r = 0; r < 8; ++r)
      m0 = fmaxf(m0, fmaxf(fmaf(gg, acc[nt][r], gv), 0.f));       // rows 0..15  (prop lo)
#pragma unroll
    for (int r = 8; r < 16; ++r)
      m1 = fmaxf(m1, fmaxf(fmaf(gg, acc[nt][r], gv), 0.f));       // rows 16..31 (prop hi)
    m0 = fmaxf(m0, __shfl_xor(m0, 32));
    m1 = fmaxf(m1, __shfl_xor(m1, 32));
    float vout = h ? m1 : m0;
    featbf[(size_t)(gw*2 + h)*128 + c] = f2bf(vout);
  }
}

// ---------------------------------------------------------------------------
// Kernel 2b: FC head via 32x32x16 bf16 MFMA — one wave per 32 proposals,
// barrier-free (private LDS slice; DS ops are in-order within a wave).
// Fragment/swizzle code identical to group_mlp layers 1/2 (validated).
// ---------------------------------------------------------------------------
__global__ __launch_bounds__(64) void fc_head_kernel(
    const unsigned short* __restrict__ featbf,
    const float* __restrict__ onx,
    const float* __restrict__ msize,
    const unsigned short* __restrict__ wfb1,
    const float* __restrict__ gf1, const float* __restrict__ gbf1,
    const unsigned short* __restrict__ wfb2,
    const float* __restrict__ gf2, const float* __restrict__ gbf2,
    const unsigned short* __restrict__ w3pb,
    const float* __restrict__ b3,
    float* __restrict__ out)
{
  __shared__ __align__(16) unsigned short actw[4096];   // 8 KiB, one wave
  const int lane = threadIdx.x;
  const int s  = lane & 31;        // A row (proposal) / B-D col bits
  const int h  = lane >> 5;        // K-half
  const int n0 = s;
  const int p0 = blockIdx.x * 32;  // this wave's 32 proposals

  f32x16 acc[4];

  // ---- FC1 (relu6): A = featbf rows p0..p0+31, K = 128
#pragma unroll
  for (int nt = 0; nt < 4; ++nt) acc[nt] = (f32x16)(0.f);
#pragma unroll
  for (int ks = 0; ks < 8; ++ks) {
    bf16x8 a = *(const bf16x8*)(featbf + (((size_t)(p0 + s)) << 7) + ks*16 + h*8);
    const unsigned short* wp = wfb1 + (size_t)n0*128 + ks*16 + h*8;
#pragma unroll
    for (int nt = 0; nt < 4; ++nt) {
      bf16x8 bb = *(const bf16x8*)(wp + (size_t)nt*32*128);
      acc[nt] = __builtin_amdgcn_mfma_f32_32x32x16_bf16(a, bb, acc[nt], 0, 0, 0);
    }
  }
#pragma unroll
  for (int nt = 0; nt < 4; ++nt) {
    int c = nt*32 + n0;
    int gch = c >> 3;
    float gg = gf1[c], gv = gbf1[c];
    int base = gch*256 + (c & 7);
#pragma unroll
    for (int r = 0; r < 16; ++r) {
      int srow = (r & 3) + 8*(r >> 2) + 4*h;
      float v = fminf(fmaxf(fmaf(gg, acc[nt][r], gv), 0.f), 6.f);
      actw[base + ((srow + 2*gch) & 31)*8] = f2bf(v);
    }
  }

  // ---- FC2 (relu6): K = 128 from LDS
#pragma unroll
  for (int nt = 0; nt < 4; ++nt) acc[nt] = (f32x16)(0.f);
#pragma unroll
  for (int ks = 0; ks < 8; ++ks) {
    int g = ks*2 + h;
    bf16x8 a = *(const bf16x8*)(actw + g*256 + ((s + 2*g) & 31)*8);
    const unsigned short* wp = wfb2 + (size_t)n0*128 + ks*16 + h*8;
#pragma unroll
    for (int nt = 0; nt < 4; ++nt) {
      bf16x8 bb = *(const bf16x8*)(wp + (size_t)nt*32*128);
      acc[nt] = __builtin_amdgcn_mfma_f32_32x32x16_bf16(a, bb, acc[nt], 0, 0, 0);
    }
  }
#pragma unroll
  for (int nt = 0; nt < 4; ++nt) {
    int c = nt*32 + n0;
    int gch = c >> 3;
    float gg = gf2[c], gv = gbf2[c];
    int base = gch*256 + (c & 7);
#pragma unroll
    for (int r = 0; r < 16; ++r) {
      int srow = (r & 3) + 8*(r >> 2) + 4*h;
      float v = fminf(fmaxf(fmaf(gg, acc[nt][r], gv), 0.f), 6.f);
      actw[base + ((srow + 2*gch) & 31)*8] = f2bf(v);
    }
  }

  // ---- FC3: K = 128, scatter with transforms
#pragma unroll
  for (int nt = 0; nt < 4; ++nt) acc[nt] = (f32x16)(0.f);
#pragma unroll
  for (int ks = 0; ks < 8; ++ks) {
    int g = ks*2 + h;
    bf16x8 a = *(const bf16x8*)(actw + g*256 + ((s + 2*g) & 31)*8);
    const unsigned short* wp = w3pb + (size_t)n0*128 + ks*16 + h*8;
#pragma unroll
    for (int nt = 0; nt < 4; ++nt) {
      bf16x8 bb = *(const bf16x8*)(wp + (size_t)nt*32*128);
      acc[nt] = __builtin_amdgcn_mfma_f32_32x32x16_bf16(a, bb, acc[nt], 0, 0, 0);
    }
  }
  const float HRC = (float)(3.14159265359 / 12.0);
#pragma unroll
  for (int nt = 0; nt < 4; ++nt) {
    int c = nt*32 + n0;
    if (c >= 119) continue;
    float b3v = b3[c];
#pragma unroll
    for (int r = 0; r < 16; ++r) {
      int srow = (r & 3) + 8*(r >> 2) + 4*h;
      int bp = p0 + srow;
      float v = acc[nt][r] + b3v;
      if (c < 3) {
        out[O_CENTER + bp*3 + c] = onx[bp*3 + c] + v;
      } else if (c < 5) {
        out[O_OBJ + bp*2 + (c-3)] = v;
      } else if (c < 17) {
        out[O_HS + bp*12 + (c-5)] = v;
      } else if (c < 35) {
        out[O_SS + bp*18 + (c-17)] = v;
      } else if (c < 47) {
        int a2 = c - 35;
        out[O_HRN + bp*12 + a2] = v;
        out[O_HR  + bp*12 + a2] = v * HRC;
      } else if (c < 101) {
        int a2 = c - 47;
        out[O_SRN + bp*54 + a2] = v;
        out[O_SR  + bp*54 + a2] = v * msize[a2];
      } else {
        int a2 = c - 101;
        out[O_SEM + bp*18 + a2] = v;
      }
    }
  }
}

// ---------------------------------------------------------------------------
extern "C" void kernel_launch(void* const* d_in, const int* in_sizes, int n_in,
                              void* d_out, int out_size, void* d_ws, size_t ws_size,
                              hipStream_t stream) {
  (void)in_sizes; (void)n_in; (void)out_size; (void)ws_size;
  const float* xyz   = (const float*)d_in[0];
  const float* feats = (const float*)d_in[1];
  const float* msize = (const float*)d_in[2];
  const float* w0  = (const float*)d_in[3];
  const float* b0  = (const float*)d_in[4];
  const float* g0  = (const float*)d_in[5];
  const float* be0 = (const float*)d_in[6];
  const float* w1  = (const float*)d_in[7];
  const float* b1  = (const float*)d_in[8];
  const float* g1  = (const float*)d_in[9];
  const float* be1 = (const float*)d_in[10];
  const float* w2  = (const float*)d_in[11];
  const float* b2  = (const float*)d_in[12];
  const float* g2  = (const float*)d_in[13];
  const float* be2 = (const float*)d_in[14];
  const float* wf1  = (const float*)d_in[15];
  const float* bf1  = (const float*)d_in[16];
  const float* gf1  = (const float*)d_in[17];
  const float* bef1 = (const float*)d_in[18];
  const float* wf2  = (const float*)d_in[19];
  const float* bf2  = (const float*)d_in[20];
  const float* gf2  = (const float*)d_in[21];
  const float* bef2 = (const float*)d_in[22];
  const float* w3 = (const float*)d_in[23];
  const float* b3 = (const float*)d_in[24];

  float* out = (float*)d_out;

  // workspace layout (bytes) — stays within the previously-used footprint
  char* wsb = (char*)d_ws;
  unsigned short* wfb1   = (unsigned short*)(wsb + 0);          //  32 KiB
  unsigned short* wfb2   = (unsigned short*)(wsb + 32768);      //  32 KiB
  unsigned short* w3pb   = (unsigned short*)(wsb + 65536);      //  32 KiB
  float*          gbf1   = (float*)         (wsb + 98304);      //  512 B
  float*          gbf2   = (float*)         (wsb + 98816);      //  512 B
  unsigned short* fbf    = (unsigned short*)(wsb + 524288);     //  16 MiB
  unsigned short* featbf = (unsigned short*)(wsb + 17301504);   //   2 MiB
  unsigned short* w0bt   = (unsigned short*)(wsb + 21495808);   //  72 KiB
  unsigned short* w1bt   = (unsigned short*)(wsb + 21569536);   //  32 KiB
  unsigned short* w2bt   = (unsigned short*)(wsb + 21602304);   //  32 KiB
  float*          gb0    = (float*)         (wsb + 21635072);   //  512 B
  float*          gb1    = (float*)         (wsb + 21635584);   //  512 B
  float*          gb2    = (float*)         (wsb + 21636096);   //  512 B

  fps_prep_kernel<<<256, 256, 0, stream>>>(
      xyz, feats, w0, w1, w2, w3,
      b0, g0, be0, b1, g1, be1, b2, g2, be2,
      wf1, bf1, gf1, bef1, wf2, bf2, gf2, bef2,
      fbf, w0bt, w1bt, w2bt, wfb1, wfb2, w3pb,
      gb0, gb1, gb2, gbf1, gbf2,
      out + O_NX, out + O_INDS);
  group_mlp_kernel<<<(BATCH*NPROP)/8, 256, 0, stream>>>(
      xyz, fbf, w0bt, w1bt, w2bt,
      g0, gb0, g1, gb1, g2, gb2,
      out + O_NX, featbf);
  fc_head_kernel<<<(BATCH*NPROP)/32, 64, 0, stream>>>(
      featbf, out + O_NX, msize,
      wfb1, gf1, gbf1, wfb2, gf2, gbf2, w3pb, b3, out);
}